// Round 1
// baseline (578.058 us; speedup 1.0000x reference)
//
#include <hip/hip_runtime.h>
#include <hip/hip_bf16.h>
#include <stdint.h>

// ---------------------------------------------------------------------------
// DMF: Monte-Carlo mutation fusion. Must reproduce JAX threefry2x32 bit-exactly.
// Mode: jax_threefry_partitionable = True (modern JAX default).
//   split(key,4):  key_i = threefry2x32(key, (0, i))              (fold-like)
//   random_bits32: bits[i] = r1 ^ r2, (r1,r2)=threefry2x32(key,(0,i))
// Fallback (legacy mode) key-derivation kept below under PARTITIONABLE==0.
// ---------------------------------------------------------------------------

#define PARTITIONABLE 1

#define NMUT 100
#define NB   1024
#define ND   512
#define NBD  (NB * ND)          // 524288 per-mutation stride
#define NCOL 1024               // output columns = 2*ND

__host__ __device__ __forceinline__ void tf2x32(uint32_t k0, uint32_t k1,
                                                uint32_t c0, uint32_t c1,
                                                uint32_t& o0, uint32_t& o1) {
  uint32_t ks2 = k0 ^ k1 ^ 0x1BD11BDAu;
  uint32_t x0 = c0 + k0;
  uint32_t x1 = c1 + k1;
#define TFR(r) { x0 += x1; x1 = (x1 << (r)) | (x1 >> (32 - (r))); x1 ^= x0; }
  TFR(13) TFR(15) TFR(26) TFR(6)
  x0 += k1;  x1 += ks2 + 1u;
  TFR(17) TFR(29) TFR(16) TFR(24)
  x0 += ks2; x1 += k0 + 2u;
  TFR(13) TFR(15) TFR(26) TFR(6)
  x0 += k0;  x1 += k1 + 3u;
  TFR(17) TFR(29) TFR(16) TFR(24)
  x0 += k1;  x1 += ks2 + 4u;
  TFR(13) TFR(15) TFR(26) TFR(6)
  x0 += ks2; x1 += k0 + 5u;
#undef TFR
  o0 = x0; o1 = x1;
}

__device__ __forceinline__ uint32_t rbits32(uint32_t k0, uint32_t k1, uint32_t idx) {
  uint32_t a, b;
  tf2x32(k0, k1, 0u, idx, a, b);
  return a ^ b;
}

// XLA ErfInv (f32): Giles polynomial. Noise values only need ~1e-6 accuracy.
__device__ __forceinline__ float erfinv_f32(float x) {
  float w = -__logf(__builtin_fmaf(-x, x, 1.0f));   // -log1p(-x*x), fma keeps precision near |x|~1
  float wa = w - 2.5f;
  float p1 = 2.81022636e-08f;
  p1 = __builtin_fmaf(p1, wa, 3.43273939e-07f);
  p1 = __builtin_fmaf(p1, wa, -3.5233877e-06f);
  p1 = __builtin_fmaf(p1, wa, -4.39150654e-06f);
  p1 = __builtin_fmaf(p1, wa, 0.00021858087f);
  p1 = __builtin_fmaf(p1, wa, -0.00125372503f);
  p1 = __builtin_fmaf(p1, wa, -0.00417768164f);
  p1 = __builtin_fmaf(p1, wa, 0.246640727f);
  p1 = __builtin_fmaf(p1, wa, 1.50140941f);
  float wb = __builtin_sqrtf(w) - 3.0f;
  float p2 = -0.000200214257f;
  p2 = __builtin_fmaf(p2, wb, 0.000100950558f);
  p2 = __builtin_fmaf(p2, wb, 0.00134934322f);
  p2 = __builtin_fmaf(p2, wb, -0.00367342844f);
  p2 = __builtin_fmaf(p2, wb, 0.00573950773f);
  p2 = __builtin_fmaf(p2, wb, -0.0076224613f);
  p2 = __builtin_fmaf(p2, wb, 0.00943887047f);
  p2 = __builtin_fmaf(p2, wb, 1.00167406f);
  p2 = __builtin_fmaf(p2, wb, 2.83297682f);
  float p = (w < 5.0f) ? p1 : p2;
  return p * x;
}

// ---- Kernel A: per-row std, ddof=1. blocks 0..1023 spatial, 1024..2047 spectral.
__global__ __launch_bounds__(256) void dmf_std(const float* __restrict__ spatial,
                                               const float* __restrict__ spectral,
                                               float* __restrict__ stds) {
  __shared__ float red[256];
  uint32_t r = blockIdx.x;
  const float* feat = (r >= NB) ? spectral : spatial;
  uint32_t row = r & (NB - 1);
  float v0 = feat[row * ND + threadIdx.x];
  float v1 = feat[row * ND + threadIdx.x + 256];
  red[threadIdx.x] = v0 + v1;
  __syncthreads();
  for (int st = 128; st > 0; st >>= 1) {
    if (threadIdx.x < (uint32_t)st) red[threadIdx.x] += red[threadIdx.x + st];
    __syncthreads();
  }
  float mean = red[0] * (1.0f / ND);
  __syncthreads();
  float d0 = v0 - mean, d1 = v1 - mean;
  red[threadIdx.x] = d0 * d0 + d1 * d1;
  __syncthreads();
  for (int st = 128; st > 0; st >>= 1) {
    if (threadIdx.x < (uint32_t)st) red[threadIdx.x] += red[threadIdx.x + st];
    __syncthreads();
  }
  if (threadIdx.x == 0) stds[r] = __builtin_sqrtf(red[0] * (1.0f / (ND - 1)));
}

// ---- Kernel B: one thread per output element (b, j). j<512 -> spatial, else spectral.
__global__ __launch_bounds__(256) void dmf_main(
    const float* __restrict__ spatial, const float* __restrict__ spectral,
    const float* __restrict__ stds, float* __restrict__ colsum,
    float* __restrict__ outP,
    uint32_t km1a, uint32_t km1b, uint32_t kn1a, uint32_t kn1b,
    uint32_t km2a, uint32_t km2b, uint32_t kn2a, uint32_t kn2b) {
  uint32_t g = blockIdx.x * 256u + threadIdx.x;
  uint32_t b = g >> 10;
  uint32_t j = g & (NCOL - 1);
  uint32_t t = j >> 9;
  uint32_t d = j & (ND - 1);

  const float* feat = t ? spectral : spatial;
  float x = feat[b * ND + d];
  float sdev = stds[t * NB + b];
  float sstd = 1.41421356237309505f * sdev;   // sqrt(2)*std folded

  uint32_t mk0 = t ? km2a : km1a, mk1 = t ? km2b : km1b;
  uint32_t nk0 = t ? kn2a : kn1a, nk1 = t ? kn2b : kn1b;

  uint32_t off = b * ND + d;
  float sd = 0.0f, sd2 = 0.0f;
#pragma unroll 2
  for (uint32_t m = 0; m < NMUT; ++m) {
    uint32_t idx = m * (uint32_t)NBD + off;
    uint32_t mb = rbits32(mk0, mk1, idx);               // mask bits
    uint32_t nb = rbits32(nk0, nk1, idx);               // noise bits
    float uf = __uint_as_float(0x3F800000u | (mb >> 9)) - 1.0f;   // [0,1)
    float nf = __uint_as_float(0x3F800000u | (nb >> 9)) - 1.0f;   // [0,1)
    // uniform(lo=-0.99999994, hi=1): (hi-lo) rounds to exactly 2.0f in f32
    float un = fmaxf(-0.99999994f, __builtin_fmaf(nf, 2.0f, -0.99999994f));
    float nrm = erfinv_f32(un) * sstd;
    float dl = (uf < 0.2f) ? nrm : 0.0f;                // delta = mask*noise*std
    sd += dl;
    sd2 = __builtin_fmaf(dl, dl, sd2);
  }
  // var over mutations of c = x + delta  ==  var of delta (ddof=0)
  float mean = sd * (1.0f / NMUT);
  float var = __builtin_fmaf(-mean, mean, sd2 * (1.0f / NMUT)) + 1e-6f;
  float iv = 1.0f / var;
  float S = __builtin_fmaf((float)NMUT, x, sd);         // sum_m c_m
  outP[g] = iv * S;
  atomicAdd(&colsum[j], iv);
}

// ---- Kernel C: normalize by column sum of invvar.
__global__ __launch_bounds__(256) void dmf_norm(float* __restrict__ out,
                                                const float* __restrict__ colsum) {
  uint32_t g = blockIdx.x * 256u + threadIdx.x;
  out[g] = out[g] / colsum[g & (NCOL - 1)];
}

extern "C" void kernel_launch(void* const* d_in, const int* in_sizes, int n_in,
                              void* d_out, int out_size, void* d_ws, size_t ws_size,
                              hipStream_t stream) {
  const float* spatial  = (const float*)d_in[0];
  const float* spectral = (const float*)d_in[1];
  float* out = (float*)d_out;
  float* ws = (float*)d_ws;
  float* colsum = ws;            // [1024]
  float* stds   = ws + 1024;     // [2048] : [0..1023] spatial std, [1024..2047] spectral std

  // Derive the 4 split keys of jax.random.key(42) on the host (pure uint32 math).
  uint32_t keys[4][2];
#if PARTITIONABLE
  for (uint32_t i = 0; i < 4; ++i)
    tf2x32(0u, 42u, 0u, i, keys[i][0], keys[i][1]);     // fold-like split
#else
  { // legacy split: counts=iota(8), pairs (i, i+4); out=[r1_0..r1_3, r2_0..r2_3]
    uint32_t a[4], b[4];
    for (uint32_t i = 0; i < 4; ++i) tf2x32(0u, 42u, i, i + 4u, a[i], b[i]);
    keys[0][0] = a[0]; keys[0][1] = a[1];   // km1
    keys[1][0] = a[2]; keys[1][1] = a[3];   // kn1
    keys[2][0] = b[0]; keys[2][1] = b[1];   // km2
    keys[3][0] = b[2]; keys[3][1] = b[3];   // kn2
  }
#endif

  hipMemsetAsync(colsum, 0, NCOL * sizeof(float), stream);
  dmf_std<<<2 * NB, 256, 0, stream>>>(spatial, spectral, stds);
  dmf_main<<<(NB * NCOL) / 256, 256, 0, stream>>>(
      spatial, spectral, stds, colsum, out,
      keys[0][0], keys[0][1], keys[1][0], keys[1][1],
      keys[2][0], keys[2][1], keys[3][0], keys[3][1]);
  dmf_norm<<<(NB * NCOL) / 256, 256, 0, stream>>>(out, colsum);
}

// Round 2
// 269.827 us; speedup vs baseline: 2.1423x; 2.1423x over previous
//
#include <hip/hip_runtime.h>
#include <hip/hip_bf16.h>
#include <stdint.h>

// ---------------------------------------------------------------------------
// DMF: Monte-Carlo mutation fusion, bit-exact JAX threefry2x32 reproduction
// (jax_threefry_partitionable=True). Round-1 version passed (absmax 2e-3).
// Round-2 change: mask-gated noise compaction. Only ~20% of noise draws
// survive the mask; queue surviving (m,lane) items per wave in LDS and
// evaluate noise threefry+erfinv in full-wave batches of 64. Delivery to the
// owner lane's accumulators via LDS f32 atomics (ds_add_f32).
// ---------------------------------------------------------------------------

#define PARTITIONABLE 1

#define NMUT 100
#define NB   1024
#define ND   512
#define NBD  (NB * ND)            // 2^19 per-mutation stride
#define NCOL 1024                 // output columns = 2*ND
// uniform(mb) < 0.2f  <=>  (mb>>9) < 1677722  <=>  mb < (1677722<<9)
#define MASK_THR 858993664u

__host__ __device__ __forceinline__ void tf2x32(uint32_t k0, uint32_t k1,
                                                uint32_t c0, uint32_t c1,
                                                uint32_t& o0, uint32_t& o1) {
  uint32_t ks2 = k0 ^ k1 ^ 0x1BD11BDAu;
  uint32_t x0 = c0 + k0;
  uint32_t x1 = c1 + k1;
#define TFR(r) { x0 += x1; x1 = __builtin_rotateleft32(x1, (r)); x1 ^= x0; }
  TFR(13) TFR(15) TFR(26) TFR(6)
  x0 += k1;  x1 += ks2 + 1u;
  TFR(17) TFR(29) TFR(16) TFR(24)
  x0 += ks2; x1 += k0 + 2u;
  TFR(13) TFR(15) TFR(26) TFR(6)
  x0 += k0;  x1 += k1 + 3u;
  TFR(17) TFR(29) TFR(16) TFR(24)
  x0 += k1;  x1 += ks2 + 4u;
  TFR(13) TFR(15) TFR(26) TFR(6)
  x0 += ks2; x1 += k0 + 5u;
#undef TFR
  o0 = x0; o1 = x1;
}

__device__ __forceinline__ uint32_t rbits32(uint32_t k0, uint32_t k1, uint32_t idx) {
  uint32_t a, b;
  tf2x32(k0, k1, 0u, idx, a, b);
  return a ^ b;
}

__device__ __forceinline__ uint32_t mbcnt64(uint64_t m) {
  return __builtin_amdgcn_mbcnt_hi((uint32_t)(m >> 32),
         __builtin_amdgcn_mbcnt_lo((uint32_t)m, 0u));
}

// XLA ErfInv (f32), Giles polynomial. Far branch (w>=5, P~=0.33%/lane) is
// wave-voted: skipped entirely when no lane needs it (~80% of batches).
__device__ __forceinline__ float erfinv_wv(float x) {
  float w = -__logf(__builtin_fmaf(-x, x, 1.0f));
  float wa = w - 2.5f;
  float p = 2.81022636e-08f;
  p = __builtin_fmaf(p, wa, 3.43273939e-07f);
  p = __builtin_fmaf(p, wa, -3.5233877e-06f);
  p = __builtin_fmaf(p, wa, -4.39150654e-06f);
  p = __builtin_fmaf(p, wa, 0.00021858087f);
  p = __builtin_fmaf(p, wa, -0.00125372503f);
  p = __builtin_fmaf(p, wa, -0.00417768164f);
  p = __builtin_fmaf(p, wa, 0.246640727f);
  p = __builtin_fmaf(p, wa, 1.50140941f);
  if (__ballot(w >= 5.0f)) {
    float wb = __builtin_amdgcn_sqrtf(w) - 3.0f;
    float p2 = -0.000200214257f;
    p2 = __builtin_fmaf(p2, wb, 0.000100950558f);
    p2 = __builtin_fmaf(p2, wb, 0.00134934322f);
    p2 = __builtin_fmaf(p2, wb, -0.00367342844f);
    p2 = __builtin_fmaf(p2, wb, 0.00573950773f);
    p2 = __builtin_fmaf(p2, wb, -0.0076224613f);
    p2 = __builtin_fmaf(p2, wb, 0.00943887047f);
    p2 = __builtin_fmaf(p2, wb, 1.00167406f);
    p2 = __builtin_fmaf(p2, wb, 2.83297682f);
    p = (w < 5.0f) ? p : p2;
  }
  return p * x;
}

// ---- Kernel A: per-row std, ddof=1. blocks 0..1023 spatial, 1024..2047 spectral.
__global__ __launch_bounds__(256) void dmf_std(const float* __restrict__ spatial,
                                               const float* __restrict__ spectral,
                                               float* __restrict__ stds) {
  __shared__ float red[256];
  uint32_t r = blockIdx.x;
  const float* feat = (r >= NB) ? spectral : spatial;
  uint32_t row = r & (NB - 1);
  float v0 = feat[row * ND + threadIdx.x];
  float v1 = feat[row * ND + threadIdx.x + 256];
  red[threadIdx.x] = v0 + v1;
  __syncthreads();
  for (int st = 128; st > 0; st >>= 1) {
    if (threadIdx.x < (uint32_t)st) red[threadIdx.x] += red[threadIdx.x + st];
    __syncthreads();
  }
  float mean = red[0] * (1.0f / ND);
  __syncthreads();
  float d0 = v0 - mean, d1 = v1 - mean;
  red[threadIdx.x] = d0 * d0 + d1 * d1;
  __syncthreads();
  for (int st = 128; st > 0; st >>= 1) {
    if (threadIdx.x < (uint32_t)st) red[threadIdx.x] += red[threadIdx.x + st];
    __syncthreads();
  }
  if (threadIdx.x == 0) stds[r] = __builtin_sqrtf(red[0] * (1.0f / (ND - 1)));
}

// ---- Kernel B: one thread per output element; wave-local noise work queue.
__global__ __launch_bounds__(256) void dmf_main(
    const float* __restrict__ spatial, const float* __restrict__ spectral,
    const float* __restrict__ stds, float* __restrict__ colsum,
    float* __restrict__ outP,
    uint32_t km1a, uint32_t km1b, uint32_t kn1a, uint32_t kn1b,
    uint32_t km2a, uint32_t km2b, uint32_t kn2a, uint32_t kn2b) {
  __shared__ uint32_t q[4][256];   // per-wave item queue: (m<<6)|lane
  __shared__ float acc[4][128];    // per-wave: acc[w][2L]=sum d, [2L+1]=sum d^2

  const uint32_t tid  = threadIdx.x;
  const uint32_t w    = tid >> 6;
  const uint32_t lane = tid & 63u;
  const uint32_t g    = blockIdx.x * 256u + tid;
  // Wave-uniform geometry: waves are 64-aligned in g, never cross b or the
  // spatial/spectral boundary (both multiples of 64).
  const uint32_t g0   = g & ~63u;
  const uint32_t b    = g0 >> 10;
  const uint32_t j0   = g0 & (NCOL - 1);
  const uint32_t t    = j0 >> 9;
  const uint32_t d0   = j0 & (ND - 1);
  const uint32_t off0 = b * ND + d0;

  acc[w][2 * lane]     = 0.0f;
  acc[w][2 * lane + 1] = 0.0f;

  const uint32_t mk0 = t ? km2a : km1a, mk1 = t ? km2b : km1b;
  const uint32_t nk0 = t ? kn2a : kn1a, nk1 = t ? kn2b : kn1b;
  const float sstd = 1.41421356237309505f * stds[t * NB + b];  // sqrt(2)*std

  auto flush_item = [&](uint32_t item) {
    uint32_t mm = item >> 6, LL = item & 63u;
    uint32_t nidx = (mm << 19) + off0 + LL;          // NBD == 2^19
    uint32_t nb = rbits32(nk0, nk1, nidx);
    float nf = __uint_as_float(0x3F800000u | (nb >> 9)) - 1.0f;  // [0,1)
    // uniform(lo=-0.99999994, hi=1): (hi-lo) == 2.0f exactly; nf>=0 => >= lo
    float un = __builtin_fmaf(nf, 2.0f, -0.99999994f);
    float nrm = erfinv_wv(un) * sstd;
    atomicAdd(&acc[w][2 * LL], nrm);
    atomicAdd(&acc[w][2 * LL + 1], nrm * nrm);
  };

  uint32_t qcount = 0, qdone = 0;
  uint32_t idx = off0 + lane;
  for (uint32_t m = 0; m < NMUT; m += 2) {
    // two independent mask threefry chains for ILP
    uint32_t mb0 = rbits32(mk0, mk1, idx);
    uint32_t mb1 = rbits32(mk0, mk1, idx + NBD);
    idx += 2u * NBD;
    uint64_t bal0 = __ballot(mb0 < MASK_THR);
    uint64_t bal1 = __ballot(mb1 < MASK_THR);
    uint32_t r0 = mbcnt64(bal0);
    uint32_t c0 = (uint32_t)__popcll(bal0);
    uint32_t r1 = mbcnt64(bal1);
    if (mb0 < MASK_THR) q[w][(qcount + r0) & 255u] = (m << 6) | lane;
    if (mb1 < MASK_THR) q[w][(qcount + c0 + r1) & 255u] = ((m + 1u) << 6) | lane;
    qcount += c0 + (uint32_t)__popcll(bal1);
    // pending <= 63 + 128 = 191 < 256: queue never overwrites unread items
    while (qcount - qdone >= 64u) {
      flush_item(q[w][(qdone + lane) & 255u]);
      qdone += 64u;
    }
  }
  uint32_t rem = qcount - qdone;
  if (lane < rem) flush_item(q[w][(qdone + lane) & 255u]);

  // DS ops within a wave complete in order: safe to read accumulators now.
  float sd  = acc[w][2 * lane];
  float sd2 = acc[w][2 * lane + 1];

  const float* feat = t ? spectral : spatial;
  float x = feat[off0 + lane];
  float mean = sd * (1.0f / NMUT);
  float var = __builtin_fmaf(-mean, mean, sd2 * (1.0f / NMUT)) + 1e-6f;
  float iv = 1.0f / var;
  float S = __builtin_fmaf((float)NMUT, x, sd);     // sum_m c_m
  outP[g] = iv * S;
  atomicAdd(&colsum[j0 + lane], iv);
}

// ---- Kernel C: normalize by column sum of invvar.
__global__ __launch_bounds__(256) void dmf_norm(float* __restrict__ out,
                                                const float* __restrict__ colsum) {
  uint32_t g = blockIdx.x * 256u + threadIdx.x;
  out[g] = out[g] / colsum[g & (NCOL - 1)];
}

extern "C" void kernel_launch(void* const* d_in, const int* in_sizes, int n_in,
                              void* d_out, int out_size, void* d_ws, size_t ws_size,
                              hipStream_t stream) {
  const float* spatial  = (const float*)d_in[0];
  const float* spectral = (const float*)d_in[1];
  float* out = (float*)d_out;
  float* ws = (float*)d_ws;
  float* colsum = ws;            // [1024]
  float* stds   = ws + 1024;     // [2048]

  uint32_t keys[4][2];
#if PARTITIONABLE
  for (uint32_t i = 0; i < 4; ++i)
    tf2x32(0u, 42u, 0u, i, keys[i][0], keys[i][1]);     // fold-like split
#else
  {
    uint32_t a[4], bb[4];
    for (uint32_t i = 0; i < 4; ++i) tf2x32(0u, 42u, i, i + 4u, a[i], bb[i]);
    keys[0][0] = a[0]; keys[0][1] = a[1];
    keys[1][0] = a[2]; keys[1][1] = a[3];
    keys[2][0] = bb[0]; keys[2][1] = bb[1];
    keys[3][0] = bb[2]; keys[3][1] = bb[3];
  }
#endif

  hipMemsetAsync(colsum, 0, NCOL * sizeof(float), stream);
  dmf_std<<<2 * NB, 256, 0, stream>>>(spatial, spectral, stds);
  dmf_main<<<(NB * NCOL) / 256, 256, 0, stream>>>(
      spatial, spectral, stds, colsum, out,
      keys[0][0], keys[0][1], keys[1][0], keys[1][1],
      keys[2][0], keys[2][1], keys[3][0], keys[3][1]);
  dmf_norm<<<(NB * NCOL) / 256, 256, 0, stream>>>(out, colsum);
}

// Round 3
// 249.547 us; speedup vs baseline: 2.3164x; 1.0813x over previous
//
#include <hip/hip_runtime.h>
#include <hip/hip_bf16.h>
#include <stdint.h>

// ---------------------------------------------------------------------------
// DMF: Monte-Carlo mutation fusion, bit-exact JAX threefry2x32 reproduction
// (jax_threefry_partitionable=True). R1: naive 634us. R2: mask-gated noise
// compaction -> 286us (VALUBusy ~97%, pure VALU-bound).
// R3 changes:
//   * force v_alignbit_b32 for threefry rotates (inline asm, device only) --
//     if LLVM was emitting lshl+lshr+or, this cuts ~40 instrs/threefry.
//   * 4-way mutation unroll: half the ballot/queue bookkeeping, more ILP.
//   * queue items packed as (m<<19)|lane so nidx = off0 + item (no decode).
//   * split delta/delta^2 accumulators -> ds_add banks 2-way (free) not 4-way.
// ---------------------------------------------------------------------------

#define NMUT 100
#define NB   1024
#define ND   512
#define NBD  (NB * ND)            // 2^19 per-mutation stride
#define NCOL 1024                 // output columns = 2*ND
// uniform(mb) < 0.2f  <=>  (mb>>9) < 1677722  <=>  mb < (1677722<<9)
#define MASK_THR 858993664u

#ifdef __HIP_DEVICE_COMPILE__
template <int R>
__device__ __forceinline__ uint32_t rotl1(uint32_t x) {
  uint32_t d;
  // rotl(x,R) == ((x:x) >> (32-R)) -- one VOP3, shift is an inline constant.
  asm("v_alignbit_b32 %0, %1, %1, %2" : "=v"(d) : "v"(x), "n"(32 - R));
  return d;
}
#define ROTL(x, r) rotl1<(r)>(x)
#else
#define ROTL(x, r) (((x) << (r)) | ((x) >> (32 - (r))))
#endif

__host__ __device__ __forceinline__ void tf2x32(uint32_t k0, uint32_t k1,
                                                uint32_t c0, uint32_t c1,
                                                uint32_t& o0, uint32_t& o1) {
  uint32_t ks2 = k0 ^ k1 ^ 0x1BD11BDAu;
  uint32_t x0 = c0 + k0;
  uint32_t x1 = c1 + k1;
#define TFR(r) { x0 += x1; x1 = ROTL(x1, r); x1 ^= x0; }
  TFR(13) TFR(15) TFR(26) TFR(6)
  x0 += k1;  x1 += ks2 + 1u;
  TFR(17) TFR(29) TFR(16) TFR(24)
  x0 += ks2; x1 += k0 + 2u;
  TFR(13) TFR(15) TFR(26) TFR(6)
  x0 += k0;  x1 += k1 + 3u;
  TFR(17) TFR(29) TFR(16) TFR(24)
  x0 += k1;  x1 += ks2 + 4u;
  TFR(13) TFR(15) TFR(26) TFR(6)
  x0 += ks2; x1 += k0 + 5u;
#undef TFR
  o0 = x0; o1 = x1;
}

__device__ __forceinline__ uint32_t rbits32(uint32_t k0, uint32_t k1, uint32_t idx) {
  uint32_t a, b;
  tf2x32(k0, k1, 0u, idx, a, b);
  return a ^ b;
}

__device__ __forceinline__ uint32_t mbcnt64(uint64_t m) {
  return __builtin_amdgcn_mbcnt_hi((uint32_t)(m >> 32),
         __builtin_amdgcn_mbcnt_lo((uint32_t)m, 0u));
}

// XLA ErfInv (f32), Giles polynomial. Far branch (w>=5, ~0.33%/lane) is
// wave-voted: skipped when no lane needs it (~80% of flush batches).
__device__ __forceinline__ float erfinv_wv(float x) {
  float w = -__logf(__builtin_fmaf(-x, x, 1.0f));
  float wa = w - 2.5f;
  float p = 2.81022636e-08f;
  p = __builtin_fmaf(p, wa, 3.43273939e-07f);
  p = __builtin_fmaf(p, wa, -3.5233877e-06f);
  p = __builtin_fmaf(p, wa, -4.39150654e-06f);
  p = __builtin_fmaf(p, wa, 0.00021858087f);
  p = __builtin_fmaf(p, wa, -0.00125372503f);
  p = __builtin_fmaf(p, wa, -0.00417768164f);
  p = __builtin_fmaf(p, wa, 0.246640727f);
  p = __builtin_fmaf(p, wa, 1.50140941f);
  if (__ballot(w >= 5.0f)) {
    float wb = __builtin_amdgcn_sqrtf(w) - 3.0f;
    float p2 = -0.000200214257f;
    p2 = __builtin_fmaf(p2, wb, 0.000100950558f);
    p2 = __builtin_fmaf(p2, wb, 0.00134934322f);
    p2 = __builtin_fmaf(p2, wb, -0.00367342844f);
    p2 = __builtin_fmaf(p2, wb, 0.00573950773f);
    p2 = __builtin_fmaf(p2, wb, -0.0076224613f);
    p2 = __builtin_fmaf(p2, wb, 0.00943887047f);
    p2 = __builtin_fmaf(p2, wb, 1.00167406f);
    p2 = __builtin_fmaf(p2, wb, 2.83297682f);
    p = (w < 5.0f) ? p : p2;
  }
  return p * x;
}

// ---- Kernel A: per-row std, ddof=1. blocks 0..1023 spatial, 1024..2047 spectral.
__global__ __launch_bounds__(256) void dmf_std(const float* __restrict__ spatial,
                                               const float* __restrict__ spectral,
                                               float* __restrict__ stds) {
  __shared__ float red[256];
  uint32_t r = blockIdx.x;
  const float* feat = (r >= NB) ? spectral : spatial;
  uint32_t row = r & (NB - 1);
  float v0 = feat[row * ND + threadIdx.x];
  float v1 = feat[row * ND + threadIdx.x + 256];
  red[threadIdx.x] = v0 + v1;
  __syncthreads();
  for (int st = 128; st > 0; st >>= 1) {
    if (threadIdx.x < (uint32_t)st) red[threadIdx.x] += red[threadIdx.x + st];
    __syncthreads();
  }
  float mean = red[0] * (1.0f / ND);
  __syncthreads();
  float d0 = v0 - mean, d1 = v1 - mean;
  red[threadIdx.x] = d0 * d0 + d1 * d1;
  __syncthreads();
  for (int st = 128; st > 0; st >>= 1) {
    if (threadIdx.x < (uint32_t)st) red[threadIdx.x] += red[threadIdx.x + st];
    __syncthreads();
  }
  if (threadIdx.x == 0) stds[r] = __builtin_sqrtf(red[0] * (1.0f / (ND - 1)));
}

// ---- Kernel B: one thread per output element; wave-local noise work queue.
__global__ __launch_bounds__(256) void dmf_main(
    const float* __restrict__ spatial, const float* __restrict__ spectral,
    const float* __restrict__ stds, float* __restrict__ colsum,
    float* __restrict__ outP,
    uint32_t km1a, uint32_t km1b, uint32_t kn1a, uint32_t kn1b,
    uint32_t km2a, uint32_t km2b, uint32_t kn2a, uint32_t kn2b) {
  __shared__ uint32_t q[4][512];   // per-wave item queue: (m<<19)|lane
  __shared__ float accd[4][64];    // per-wave: sum delta   (banks: 2-way, free)
  __shared__ float accd2[4][64];   // per-wave: sum delta^2

  const uint32_t tid  = threadIdx.x;
  const uint32_t w    = tid >> 6;
  const uint32_t lane = tid & 63u;
  const uint32_t g    = blockIdx.x * 256u + tid;
  // Wave-uniform geometry: waves are 64-aligned in g, never cross b or the
  // spatial/spectral boundary (both multiples of 64).
  const uint32_t g0   = g & ~63u;
  const uint32_t b    = g0 >> 10;
  const uint32_t j0   = g0 & (NCOL - 1);
  const uint32_t t    = j0 >> 9;
  const uint32_t d0   = j0 & (ND - 1);
  const uint32_t off0 = b * ND + d0;

  accd[w][lane]  = 0.0f;
  accd2[w][lane] = 0.0f;

  const uint32_t mk0 = t ? km2a : km1a, mk1 = t ? km2b : km1b;
  const uint32_t nk0 = t ? kn2a : kn1a, nk1 = t ? kn2b : kn1b;
  const float sstd = 1.41421356237309505f * stds[t * NB + b];  // sqrt(2)*std

  auto flush_item = [&](uint32_t pk) {       // pk = (m<<19)|ownerLane
    uint32_t LL = pk & 63u;
    uint32_t nidx = off0 + pk;               // == m*2^19 + off0 + LL (no carry)
    uint32_t nb = rbits32(nk0, nk1, nidx);
    float nf = __uint_as_float(0x3F800000u | (nb >> 9)) - 1.0f;  // [0,1)
    // uniform(lo=-0.99999994, hi=1): (hi-lo) == 2.0f exactly; nf>=0 => >= lo
    float un = __builtin_fmaf(nf, 2.0f, -0.99999994f);
    float nrm = erfinv_wv(un) * sstd;
    atomicAdd(&accd[w][LL], nrm);
    atomicAdd(&accd2[w][LL], nrm * nrm);
  };

  uint32_t qcount = 0, qdone = 0;
  uint32_t idx = off0 + lane;
#pragma unroll 1
  for (uint32_t m = 0; m < NMUT; m += 4) {
    // four independent mask threefry chains for ILP
    uint32_t mb0 = rbits32(mk0, mk1, idx);
    uint32_t mb1 = rbits32(mk0, mk1, idx + NBD);
    uint32_t mb2 = rbits32(mk0, mk1, idx + 2u * NBD);
    uint32_t mb3 = rbits32(mk0, mk1, idx + 3u * NBD);
    idx += 4u * NBD;
    uint64_t B0 = __ballot(mb0 < MASK_THR);
    uint64_t B1 = __ballot(mb1 < MASK_THR);
    uint64_t B2 = __ballot(mb2 < MASK_THR);
    uint64_t B3 = __ballot(mb3 < MASK_THR);
    uint32_t base = qcount;
    if (mb0 < MASK_THR) q[w][(base + mbcnt64(B0)) & 511u] = (m << 19) | lane;
    base += (uint32_t)__popcll(B0);
    if (mb1 < MASK_THR) q[w][(base + mbcnt64(B1)) & 511u] = ((m + 1u) << 19) | lane;
    base += (uint32_t)__popcll(B1);
    if (mb2 < MASK_THR) q[w][(base + mbcnt64(B2)) & 511u] = ((m + 2u) << 19) | lane;
    base += (uint32_t)__popcll(B2);
    if (mb3 < MASK_THR) q[w][(base + mbcnt64(B3)) & 511u] = ((m + 3u) << 19) | lane;
    qcount = base + (uint32_t)__popcll(B3);
    // pending <= 63 + 256 = 319 < 512: queue never overwrites unread items
    while (qcount - qdone >= 64u) {
      flush_item(q[w][(qdone + lane) & 511u]);
      qdone += 64u;
    }
  }
  uint32_t rem = qcount - qdone;
  if (lane < rem) flush_item(q[w][(qdone + lane) & 511u]);

  // DS ops from this wave complete in issue order: accumulators are final.
  float sd  = accd[w][lane];
  float sd2 = accd2[w][lane];

  const float* feat = t ? spectral : spatial;
  float x = feat[off0 + lane];
  float mean = sd * (1.0f / NMUT);
  float var = __builtin_fmaf(-mean, mean, sd2 * (1.0f / NMUT)) + 1e-6f;
  float iv = 1.0f / var;
  float S = __builtin_fmaf((float)NMUT, x, sd);     // sum_m c_m
  outP[g] = iv * S;
  atomicAdd(&colsum[j0 + lane], iv);
}

// ---- Kernel C: normalize by column sum of invvar.
__global__ __launch_bounds__(256) void dmf_norm(float* __restrict__ out,
                                                const float* __restrict__ colsum) {
  uint32_t g = blockIdx.x * 256u + threadIdx.x;
  out[g] = out[g] / colsum[g & (NCOL - 1)];
}

extern "C" void kernel_launch(void* const* d_in, const int* in_sizes, int n_in,
                              void* d_out, int out_size, void* d_ws, size_t ws_size,
                              hipStream_t stream) {
  const float* spatial  = (const float*)d_in[0];
  const float* spectral = (const float*)d_in[1];
  float* out = (float*)d_out;
  float* ws = (float*)d_ws;
  float* colsum = ws;            // [1024]
  float* stds   = ws + 1024;     // [2048]

  // Derive the 4 split keys of jax.random.key(42) on the host (pure u32 math;
  // partitionable split is fold-like: key_i = threefry2x32(key, (0, i))).
  uint32_t keys[4][2];
  for (uint32_t i = 0; i < 4; ++i)
    tf2x32(0u, 42u, 0u, i, keys[i][0], keys[i][1]);

  hipMemsetAsync(colsum, 0, NCOL * sizeof(float), stream);
  dmf_std<<<2 * NB, 256, 0, stream>>>(spatial, spectral, stds);
  dmf_main<<<(NB * NCOL) / 256, 256, 0, stream>>>(
      spatial, spectral, stds, colsum, out,
      keys[0][0], keys[0][1], keys[1][0], keys[1][1],
      keys[2][0], keys[2][1], keys[3][0], keys[3][1]);
  dmf_norm<<<(NB * NCOL) / 256, 256, 0, stream>>>(out, colsum);
}